// Round 1
// baseline (211.318 us; speedup 1.0000x reference)
//
#include <hip/hip_runtime.h>

#define NT 256          // f(x) table size
#define NBATCH 1024
#define NOUT 65536      // 1024*64

// ---- graph constants (baked from the reference) ----
__constant__ int c_e1[17] = {0,0,1,2,2,3,4,5,6,8,8,9,10,11,11,13,14};
__constant__ int c_e2[17] = {1,4,2,3,5,4,12,6,7,9,12,10,11,12,13,14,15};
__constant__ int c_p0[24] = {1,0,1,1,3,2,0,0,3,2,5,5,9,8,9,10,10,12,4,4,8,11,13,13};
__constant__ int c_p1[24] = {4,2,3,5,5,4,3,12,12,6,7,6,12,10,11,11,13,13,8,11,11,14,15,14};
__constant__ int c_ni[24] = {0,1,2,2,2,3,4,4,4,5,6,7,8,9,10,11,11,11,12,12,12,13,14,15};

// monotonic float<->uint encoding for atomicMin/Max on floats
__device__ __forceinline__ unsigned encf(float f) {
  unsigned u = __float_as_uint(f);
  return (u & 0x80000000u) ? ~u : (u | 0x80000000u);
}
__device__ __forceinline__ float decf(unsigned e) {
  unsigned u = (e & 0x80000000u) ? (e & 0x7FFFFFFFu) : ~e;
  return __uint_as_float(u);
}

__global__ void k_init(unsigned* __restrict__ mm) {
  mm[0] = 0xFFFFFFFFu;  // running min (encoded)
  mm[1] = 0u;           // running max (encoded)
}

// ---- kernel 1: per-batch ovl (8x8) = sum_{a,b} pref_ab * C_a E_ab C_b^T ----
__global__ __launch_bounds__(256)
void k_ovl(const float* __restrict__ pos, const float* __restrict__ cg,
           const float* __restrict__ sigp, float* __restrict__ xout,
           unsigned* __restrict__ mm) {
  __shared__ float posS[16][3];
  __shared__ float P[81][3];
  __shared__ __align__(16) float CT[243][8];   // C' transposed: CT[j][q]
  __shared__ float d2s[81][81];
  __shared__ float Vr[81][8];
  __shared__ float Wr[81][8];
  __shared__ float ovl_s[64];

  const int b = blockIdx.x;
  const int t = threadIdx.x;

  if (t < 48) ((float*)posS)[t] = pos[b * 48 + t];

  // make_opposite_blocks forward: odd cross cols (within each 81-block) = -C[:,j-1]
  for (int idx = t; idx < 243 * 8; idx += 256) {
    int j = idx >> 3, q = idx & 7;
    int bp = j % 81;
    int off = bp - 33;
    float v;
    if (off >= 0 && (off & 1)) v = -cg[q * 243 + (j - 1)];
    else                       v =  cg[q * 243 + j];
    CT[j][q] = v;
  }
  if (t < 64) ovl_s[t] = 0.0f;
  __syncthreads();

  // 81 block points: 16 atoms, 17 bond midpoints, 24 pairs x 2 cross points
  if (t < 81) {
    float x, y, z;
    if (t < 16) {
      x = posS[t][0]; y = posS[t][1]; z = posS[t][2];
    } else if (t < 33) {
      int e = t - 16;
      int a0 = c_e1[e], a1 = c_e2[e];
      x = 0.5f * (posS[a0][0] + posS[a1][0]);
      y = 0.5f * (posS[a0][1] + posS[a1][1]);
      z = 0.5f * (posS[a0][2] + posS[a1][2]);
    } else {
      int k = (t - 33) >> 1, s = (t - 33) & 1;
      float sc = s ? 0.25f : -0.25f;
      int n = c_ni[k], a0 = c_p0[k], a1 = c_p1[k];
      x = posS[n][0] + sc * (posS[a0][0] - posS[a1][0]);
      y = posS[n][1] + sc * (posS[a0][1] - posS[a1][1]);
      z = posS[n][2] + sc * (posS[a0][2] - posS[a1][2]);
    }
    P[t][0] = x; P[t][1] = y; P[t][2] = z;
  }
  __syncthreads();

  for (int idx = t; idx < 81 * 81; idx += 256) {
    int i = idx / 81;
    int j = idx - i * 81;
    float dx = P[i][0] - P[j][0];
    float dy = P[i][1] - P[j][1];
    float dz = P[i][2] - P[j][2];
    d2s[i][j] = dx * dx + dy * dy + dz * dz;
  }

  float sgl[3];
  sgl[0] = 0.4f * __expf(sigp[0]);
  sgl[1] = 0.8f * __expf(sigp[1]);
  sgl[2] = 1.2f * __expf(sigp[2]);
  __syncthreads();

  const int ca_[6] = {0, 0, 0, 1, 1, 2};
  const int cb_[6] = {0, 1, 2, 1, 2, 2};
  const int i81 = t % 81;  // row of E owned by this thread
  const int ch  = t / 81;  // 27-wide j-chunk (0..2); t>=243 idle

  for (int c6 = 0; c6 < 6; ++c6) {
    const int a = ca_[c6], bb = cb_[c6];
    const float sa = sgl[a], sb = sgl[bb];
    const float s2 = sa * sa + sb * sb;
    const float rr = 2.0f * sa * sb / s2;
    const float pref = rr * sqrtf(rr);     // rr^1.5
    const float nInv = -0.5f / s2;

    for (int idx = t; idx < 81 * 8; idx += 256) {
      ((float*)Vr)[idx] = 0.0f;
      ((float*)Wr)[idx] = 0.0f;
    }
    __syncthreads();

    if (t < 243) {
      float aV[8] = {0,0,0,0,0,0,0,0};
      float aW[8] = {0,0,0,0,0,0,0,0};
      const int j0 = ch * 27;
      const bool diag = (a == bb);
      for (int jj = 0; jj < 27; ++jj) {
        const int j = j0 + jj;
        const float e = __expf(d2s[i81][j] * nInv);
        const float4 cb0 = *(const float4*)&CT[bb * 81 + j][0];
        const float4 cb1 = *(const float4*)&CT[bb * 81 + j][4];
        aV[0] += e * cb0.x; aV[1] += e * cb0.y; aV[2] += e * cb0.z; aV[3] += e * cb0.w;
        aV[4] += e * cb1.x; aV[5] += e * cb1.y; aV[6] += e * cb1.z; aV[7] += e * cb1.w;
        if (!diag) {
          const float4 ca0 = *(const float4*)&CT[a * 81 + j][0];
          const float4 ca1 = *(const float4*)&CT[a * 81 + j][4];
          aW[0] += e * ca0.x; aW[1] += e * ca0.y; aW[2] += e * ca0.z; aW[3] += e * ca0.w;
          aW[4] += e * ca1.x; aW[5] += e * ca1.y; aW[6] += e * ca1.z; aW[7] += e * ca1.w;
        }
      }
      #pragma unroll
      for (int q = 0; q < 8; ++q) atomicAdd(&Vr[i81][q], aV[q]);
      if (!diag) {
        #pragma unroll
        for (int q = 0; q < 8; ++q) atomicAdd(&Wr[i81][q], aW[q]);
      }
    }
    __syncthreads();

    if (t < 64) {  // ovl += pref*(C_a V + [a!=b] C_b W)
      const int p = t >> 3, q = t & 7;
      float s = 0.0f;
      if (a == bb) {
        for (int i2 = 0; i2 < 81; ++i2)
          s += CT[a * 81 + i2][p] * Vr[i2][q];
      } else {
        for (int i2 = 0; i2 < 81; ++i2)
          s += CT[a * 81 + i2][p] * Vr[i2][q] + CT[bb * 81 + i2][p] * Wr[i2][q];
      }
      ovl_s[t] += pref * s;
    }
    __syncthreads();
  }

  if (t < 64) {
    const float v = ovl_s[t];
    xout[b * 64 + t] = v;
    float vmin = v, vmax = v;
    #pragma unroll
    for (int off = 32; off; off >>= 1) {
      vmin = fminf(vmin, __shfl_down(vmin, off));
      vmax = fmaxf(vmax, __shfl_down(vmax, off));
    }
    if (t == 0) {
      atomicMin(&mm[0], encf(vmin));
      atomicMax(&mm[1], encf(vmax));
    }
  }
}

// ---- kernel 2: tabulate f(x) at NT nodes; full fp32 MLP per node ----
__device__ __forceinline__ float dot128(const float* __restrict__ W,
                                        const float* __restrict__ act, int t) {
  const float4* w4 = (const float4*)(W + (size_t)t * 128);
  const float4* a4 = (const float4*)act;
  float acc = 0.0f;
  #pragma unroll
  for (int kq = 0; kq < 32; ++kq) {
    float4 w = w4[kq];
    float4 a = a4[kq];
    acc += w.x * a.x + w.y * a.y + w.z * a.z + w.w * a.w;
  }
  return acc;
}

__global__ __launch_bounds__(128)
void k_table(const float* __restrict__ ew, const float* __restrict__ eb,
             const float* __restrict__ mup, const float* __restrict__ lrp,
             const float* __restrict__ W1, const float* __restrict__ b1,
             const float* __restrict__ W2, const float* __restrict__ b2,
             const float* __restrict__ W3, const float* __restrict__ b3,
             const unsigned* __restrict__ mm, float* __restrict__ table) {
  __shared__ __align__(16) float actA[128];
  __shared__ __align__(16) float actB[128];
  __shared__ float red[2];
  __shared__ float red2[2];
  const int t = threadIdx.x;
  const int wv = t >> 6;

  const float xmin = decf(mm[0]);
  const float xmax = decf(mm[1]);
  const float x = xmin + (xmax - xmin) * ((float)blockIdx.x / (float)(NT - 1));

  // encoder softmax: e = softmax(ew*x + eb)
  float lg = ew[t] * x + eb[t];
  float m = lg;
  #pragma unroll
  for (int off = 32; off; off >>= 1) m = fmaxf(m, __shfl_xor(m, off));
  if ((t & 63) == 0) red[wv] = m;
  __syncthreads();
  m = fmaxf(red[0], red[1]);
  float ev = __expf(lg - m);
  float s = ev;
  #pragma unroll
  for (int off = 32; off; off >>= 1) s += __shfl_xor(s, off);
  if ((t & 63) == 0) red2[wv] = s;
  __syncthreads();
  s = red2[0] + red2[1];
  actA[t] = ev / s;
  __syncthreads();

  // layer 1 (relu)
  float h = fmaxf(b1[t] + dot128(W1, actA, t), 0.0f);
  actB[t] = h;
  __syncthreads();
  // layer 2 (relu)
  h = fmaxf(b2[t] + dot128(W2, actB, t), 0.0f);
  actA[t] = h;
  __syncthreads();
  // layer 3 (linear)
  float h3 = b3[t] + dot128(W3, actA, t);

  // p = softmax(h3); mu = p . mu_proj  (fused)
  float m3 = h3;
  #pragma unroll
  for (int off = 32; off; off >>= 1) m3 = fmaxf(m3, __shfl_xor(m3, off));
  __syncthreads();
  if ((t & 63) == 0) red[wv] = m3;
  __syncthreads();
  m3 = fmaxf(red[0], red[1]);
  float e3 = __expf(h3 - m3);
  float dn = e3;
  float nm = e3 * mup[t];
  #pragma unroll
  for (int off = 32; off; off >>= 1) {
    dn += __shfl_xor(dn, off);
    nm += __shfl_xor(nm, off);
  }
  __syncthreads();
  if ((t & 63) == 0) { red[wv] = dn; red2[wv] = nm; }
  __syncthreads();
  if (t == 0)
    table[blockIdx.x] = lrp[0] * ((red2[0] + red2[1]) / (red[0] + red[1]));
}

// ---- kernel 3: linear interpolation of the table at each x ----
__global__ __launch_bounds__(256)
void k_interp(const float* __restrict__ xbuf, const float* __restrict__ table,
              const unsigned* __restrict__ mm, float* __restrict__ out, int n) {
  const int r = blockIdx.x * 256 + threadIdx.x;
  if (r >= n) return;
  const float xmin = decf(mm[0]);
  const float xmax = decf(mm[1]);
  const float range = xmax - xmin;
  const float scale = (range > 0.0f) ? (float)(NT - 1) / range : 0.0f;
  float p = (xbuf[r] - xmin) * scale;
  int i0 = (int)floorf(p);
  i0 = min(max(i0, 0), NT - 2);
  const float w = p - (float)i0;
  out[r] = table[i0] + w * (table[i0 + 1] - table[i0]);
}

extern "C" void kernel_launch(void* const* d_in, const int* in_sizes, int n_in,
                              void* d_out, int out_size, void* d_ws, size_t ws_size,
                              hipStream_t stream) {
  const float* pos  = (const float*)d_in[0];
  const float* cg   = (const float*)d_in[1];
  const float* sigp = (const float*)d_in[2];
  const float* ew   = (const float*)d_in[3];
  const float* eb   = (const float*)d_in[4];
  const float* mup  = (const float*)d_in[5];
  const float* lrp  = (const float*)d_in[6];
  const float* W1   = (const float*)d_in[7];
  const float* b1   = (const float*)d_in[8];
  const float* W2   = (const float*)d_in[9];
  const float* b2   = (const float*)d_in[10];
  const float* W3   = (const float*)d_in[11];
  const float* b3   = (const float*)d_in[12];
  float* out = (float*)d_out;

  // workspace: [0..1] uint min/max (encoded), xbuf[65536] @ +16 floats, table[NT]
  unsigned* mm = (unsigned*)d_ws;
  float* xbuf  = (float*)d_ws + 16;
  float* table = xbuf + NOUT;

  k_init<<<1, 1, 0, stream>>>(mm);
  k_ovl<<<NBATCH, 256, 0, stream>>>(pos, cg, sigp, xbuf, mm);
  k_table<<<NT, 128, 0, stream>>>(ew, eb, mup, lrp, W1, b1, W2, b2, W3, b3, mm, table);
  k_interp<<<(NOUT + 255) / 256, 256, 0, stream>>>(xbuf, table, mm, out, NOUT);
}

// Round 2
// 68.503 us; speedup vs baseline: 3.0848x; 3.0848x over previous
//
#include <hip/hip_runtime.h>

#define NT 256          // f(x) table size
#define NBATCH 1024
#define NOUT 65536      // 1024*64

// ---- graph constants (baked from the reference) ----
__constant__ int c_e1[17] = {0,0,1,2,2,3,4,5,6,8,8,9,10,11,11,13,14};
__constant__ int c_e2[17] = {1,4,2,3,5,4,12,6,7,9,12,10,11,12,13,14,15};
__constant__ int c_p0[24] = {1,0,1,1,3,2,0,0,3,2,5,5,9,8,9,10,10,12,4,4,8,11,13,13};
__constant__ int c_p1[24] = {4,2,3,5,5,4,3,12,12,6,7,6,12,10,11,11,13,13,8,11,11,14,15,14};
__constant__ int c_ni[24] = {0,1,2,2,2,3,4,4,4,5,6,7,8,9,10,11,11,11,12,12,12,13,14,15};

// 9 ordered products s: E-scale combo c_s, j-side (right C), left-side (stage-2 C)
__constant__ int c_cOf[9]   = {0,1,1,2,2,3,4,4,5};
__constant__ int c_jside[9] = {0,1,0,2,0,1,2,1,2};
__constant__ int c_left[9]  = {0,0,1,0,2,1,1,2,2};
__constant__ int c_ca[6] = {0,0,0,1,1,2};
__constant__ int c_cb[6] = {0,1,2,1,2,2};

// monotonic float<->uint encoding for atomicMin/Max on floats
__device__ __forceinline__ unsigned encf(float f) {
  unsigned u = __float_as_uint(f);
  return (u & 0x80000000u) ? ~u : (u | 0x80000000u);
}
__device__ __forceinline__ float decf(unsigned e) {
  unsigned u = (e & 0x80000000u) ? (e & 0x7FFFFFFFu) : ~e;
  return __uint_as_float(u);
}

__global__ void k_init(unsigned* __restrict__ mm) {
  mm[0] = 0xFFFFFFFFu;  // running min (encoded)
  mm[1] = 0u;           // running max (encoded)
}

// ---- kernel 1: per-batch ovl (8x8) = sum_s pref_s * C_left^T E_c C_jside ----
__global__ __launch_bounds__(256, 4)
void k_ovl(const float* __restrict__ pos, const float* __restrict__ cg,
           const float* __restrict__ sigp, float* __restrict__ xout,
           unsigned* __restrict__ mm) {
  __shared__ float posS[48];
  __shared__ __align__(16) float P4[81][4];
  __shared__ __align__(16) float CT[3][81][8];    // C' transposed per block: CT[s][j][q]
  __shared__ __align__(16) float Vall[9][81][8];  // V rows for all 9 products
  __shared__ float nInvL[9], prefL[9];
  __shared__ float red[4][64];

  const int b = blockIdx.x;
  const int t = threadIdx.x;

  if (t < 48) posS[t] = pos[b * 48 + t];

  // make_opposite_blocks forward: odd cross cols (bp>=33, odd offset) = -C[:,col-1]
  for (int idx = t; idx < 3 * 81 * 8; idx += 256) {
    int s = idx / 648;
    int rem = idx - s * 648;
    int j = rem >> 3, q = rem & 7;
    int col = s * 81 + j;
    int off = j - 33;                 // block-local position minus N1
    float v;
    if (off >= 0 && (off & 1)) v = -cg[q * 243 + (col - 1)];
    else                       v =  cg[q * 243 + col];
    CT[s][j][q] = v;
  }

  if (t == 0) {
    float sgl0 = 0.4f * __expf(sigp[0]);
    float sgl1 = 0.8f * __expf(sigp[1]);
    float sgl2 = 1.2f * __expf(sigp[2]);
    float sg[3] = {sgl0, sgl1, sgl2};
    float nI[6], pf[6];
    #pragma unroll
    for (int c = 0; c < 6; ++c) {
      float sa = sg[c_ca[c]], sb = sg[c_cb[c]];
      float s2 = sa * sa + sb * sb;
      float rr = 2.0f * sa * sb / s2;
      pf[c] = rr * sqrtf(rr);
      nI[c] = -0.5f / s2;
    }
    #pragma unroll
    for (int s = 0; s < 9; ++s) {
      nInvL[s] = nI[c_cOf[s]];
      prefL[s] = pf[c_cOf[s]];
    }
  }
  __syncthreads();

  // 81 block points: 16 atoms, 17 bond midpoints, 24 pairs x 2 cross points
  if (t < 81) {
    float x, y, z;
    if (t < 16) {
      x = posS[t * 3]; y = posS[t * 3 + 1]; z = posS[t * 3 + 2];
    } else if (t < 33) {
      int e = t - 16;
      int a0 = c_e1[e] * 3, a1 = c_e2[e] * 3;
      x = 0.5f * (posS[a0] + posS[a1]);
      y = 0.5f * (posS[a0 + 1] + posS[a1 + 1]);
      z = 0.5f * (posS[a0 + 2] + posS[a1 + 2]);
    } else {
      int k = (t - 33) >> 1, sgn = (t - 33) & 1;
      float sc = sgn ? 0.25f : -0.25f;
      int n = c_ni[k] * 3, a0 = c_p0[k] * 3, a1 = c_p1[k] * 3;
      x = posS[n]     + sc * (posS[a0]     - posS[a1]);
      y = posS[n + 1] + sc * (posS[a0 + 1] - posS[a1 + 1]);
      z = posS[n + 2] + sc * (posS[a0 + 2] - posS[a1 + 2]);
    }
    P4[t][0] = x; P4[t][1] = y; P4[t][2] = z; P4[t][3] = 0.0f;
  }
  __syncthreads();

  // ---- V phase: 729 independent row-tasks, no atomics, no barriers ----
  for (int tau = t; tau < 729; tau += 256) {
    const int s = tau / 81;
    const int i = tau - s * 81;
    const int js = c_jside[s];
    const float nInv = nInvL[s];
    const float4 pi4 = *(const float4*)P4[i];
    float a0 = 0, a1 = 0, a2 = 0, a3 = 0, a4 = 0, a5 = 0, a6 = 0, a7 = 0;
    #pragma unroll 3
    for (int j = 0; j < 81; ++j) {
      const float4 pj = *(const float4*)P4[j];
      const float dx = pi4.x - pj.x;
      const float dy = pi4.y - pj.y;
      const float dz = pi4.z - pj.z;
      const float e = __expf((dx * dx + dy * dy + dz * dz) * nInv);
      const float4 cb0 = *(const float4*)&CT[js][j][0];
      const float4 cb1 = *(const float4*)&CT[js][j][4];
      a0 += e * cb0.x; a1 += e * cb0.y; a2 += e * cb0.z; a3 += e * cb0.w;
      a4 += e * cb1.x; a5 += e * cb1.y; a6 += e * cb1.z; a7 += e * cb1.w;
    }
    float4* vo = (float4*)&Vall[s][i][0];
    vo[0] = make_float4(a0, a1, a2, a3);
    vo[1] = make_float4(a4, a5, a6, a7);
  }
  __syncthreads();

  // ---- stage 2: ovl[p][q] = sum_s pref_s sum_i CT[left_s][i][p]*Vall[s][i][q]
  {
    const int w = t >> 6;
    const int pos64 = t & 63;
    const int p = pos64 >> 3, q = pos64 & 7;
    float part = 0.0f;
    for (int s = w; s < 9; s += 4) {
      const int lf = c_left[s];
      const float pf = prefL[s];
      float ss = 0.0f;
      #pragma unroll 9
      for (int i = 0; i < 81; ++i)
        ss += CT[lf][i][p] * Vall[s][i][q];
      part += pf * ss;
    }
    red[w][pos64] = part;
  }
  __syncthreads();

  if (t < 64) {
    const float v = red[0][t] + red[1][t] + red[2][t] + red[3][t];
    xout[b * 64 + t] = v;
    float vmin = v, vmax = v;
    #pragma unroll
    for (int off = 32; off; off >>= 1) {
      vmin = fminf(vmin, __shfl_down(vmin, off));
      vmax = fmaxf(vmax, __shfl_down(vmax, off));
    }
    if (t == 0) {
      atomicMin(&mm[0], encf(vmin));
      atomicMax(&mm[1], encf(vmax));
    }
  }
}

// ---- kernel 2: tabulate f(x) at NT nodes; full fp32 MLP per node ----
__device__ __forceinline__ float dot128(const float* __restrict__ W,
                                        const float* __restrict__ act, int t) {
  const float4* w4 = (const float4*)(W + (size_t)t * 128);
  const float4* a4 = (const float4*)act;
  float acc = 0.0f;
  #pragma unroll
  for (int kq = 0; kq < 32; ++kq) {
    float4 w = w4[kq];
    float4 a = a4[kq];
    acc += w.x * a.x + w.y * a.y + w.z * a.z + w.w * a.w;
  }
  return acc;
}

__global__ __launch_bounds__(128)
void k_table(const float* __restrict__ ew, const float* __restrict__ eb,
             const float* __restrict__ mup, const float* __restrict__ lrp,
             const float* __restrict__ W1, const float* __restrict__ b1,
             const float* __restrict__ W2, const float* __restrict__ b2,
             const float* __restrict__ W3, const float* __restrict__ b3,
             const unsigned* __restrict__ mm, float* __restrict__ table) {
  __shared__ __align__(16) float actA[128];
  __shared__ __align__(16) float actB[128];
  __shared__ float red[2];
  __shared__ float red2[2];
  const int t = threadIdx.x;
  const int wv = t >> 6;

  const float xmin = decf(mm[0]);
  const float xmax = decf(mm[1]);
  const float x = xmin + (xmax - xmin) * ((float)blockIdx.x / (float)(NT - 1));

  // encoder softmax: e = softmax(ew*x + eb)
  float lg = ew[t] * x + eb[t];
  float m = lg;
  #pragma unroll
  for (int off = 32; off; off >>= 1) m = fmaxf(m, __shfl_xor(m, off));
  if ((t & 63) == 0) red[wv] = m;
  __syncthreads();
  m = fmaxf(red[0], red[1]);
  float ev = __expf(lg - m);
  float s = ev;
  #pragma unroll
  for (int off = 32; off; off >>= 1) s += __shfl_xor(s, off);
  if ((t & 63) == 0) red2[wv] = s;
  __syncthreads();
  s = red2[0] + red2[1];
  actA[t] = ev / s;
  __syncthreads();

  // layer 1 (relu)
  float h = fmaxf(b1[t] + dot128(W1, actA, t), 0.0f);
  actB[t] = h;
  __syncthreads();
  // layer 2 (relu)
  h = fmaxf(b2[t] + dot128(W2, actB, t), 0.0f);
  actA[t] = h;
  __syncthreads();
  // layer 3 (linear)
  float h3 = b3[t] + dot128(W3, actA, t);

  // p = softmax(h3); mu = p . mu_proj  (fused)
  float m3 = h3;
  #pragma unroll
  for (int off = 32; off; off >>= 1) m3 = fmaxf(m3, __shfl_xor(m3, off));
  __syncthreads();
  if ((t & 63) == 0) red[wv] = m3;
  __syncthreads();
  m3 = fmaxf(red[0], red[1]);
  float e3 = __expf(h3 - m3);
  float dn = e3;
  float nm = e3 * mup[t];
  #pragma unroll
  for (int off = 32; off; off >>= 1) {
    dn += __shfl_xor(dn, off);
    nm += __shfl_xor(nm, off);
  }
  __syncthreads();
  if ((t & 63) == 0) { red[wv] = dn; red2[wv] = nm; }
  __syncthreads();
  if (t == 0)
    table[blockIdx.x] = lrp[0] * ((red2[0] + red2[1]) / (red[0] + red[1]));
}

// ---- kernel 3: linear interpolation of the table at each x ----
__global__ __launch_bounds__(256)
void k_interp(const float* __restrict__ xbuf, const float* __restrict__ table,
              const unsigned* __restrict__ mm, float* __restrict__ out, int n) {
  const int r = blockIdx.x * 256 + threadIdx.x;
  if (r >= n) return;
  const float xmin = decf(mm[0]);
  const float xmax = decf(mm[1]);
  const float range = xmax - xmin;
  const float scale = (range > 0.0f) ? (float)(NT - 1) / range : 0.0f;
  float p = (xbuf[r] - xmin) * scale;
  int i0 = (int)floorf(p);
  i0 = min(max(i0, 0), NT - 2);
  const float w = p - (float)i0;
  out[r] = table[i0] + w * (table[i0 + 1] - table[i0]);
}

extern "C" void kernel_launch(void* const* d_in, const int* in_sizes, int n_in,
                              void* d_out, int out_size, void* d_ws, size_t ws_size,
                              hipStream_t stream) {
  const float* pos  = (const float*)d_in[0];
  const float* cg   = (const float*)d_in[1];
  const float* sigp = (const float*)d_in[2];
  const float* ew   = (const float*)d_in[3];
  const float* eb   = (const float*)d_in[4];
  const float* mup  = (const float*)d_in[5];
  const float* lrp  = (const float*)d_in[6];
  const float* W1   = (const float*)d_in[7];
  const float* b1   = (const float*)d_in[8];
  const float* W2   = (const float*)d_in[9];
  const float* b2   = (const float*)d_in[10];
  const float* W3   = (const float*)d_in[11];
  const float* b3   = (const float*)d_in[12];
  float* out = (float*)d_out;

  // workspace: [0..1] uint min/max (encoded), xbuf[65536] @ +16 floats, table[NT]
  unsigned* mm = (unsigned*)d_ws;
  float* xbuf  = (float*)d_ws + 16;
  float* table = xbuf + NOUT;

  k_init<<<1, 1, 0, stream>>>(mm);
  k_ovl<<<NBATCH, 256, 0, stream>>>(pos, cg, sigp, xbuf, mm);
  k_table<<<NT, 128, 0, stream>>>(ew, eb, mup, lrp, W1, b1, W2, b2, W3, b3, mm, table);
  k_interp<<<(NOUT + 255) / 256, 256, 0, stream>>>(xbuf, table, mm, out, NOUT);
}

// Round 3
// 58.784 us; speedup vs baseline: 3.5948x; 1.1653x over previous
//
#include <hip/hip_runtime.h>

#define NT 256          // f(x) table size
#define NBATCH 1024
#define NOUT 65536      // 1024*64

#if __has_builtin(__builtin_amdgcn_exp2f)
#define EXP2(x) __builtin_amdgcn_exp2f(x)
#else
#define EXP2(x) exp2f(x)
#endif

// ---- graph constants (baked from the reference) ----
__constant__ int c_e1[17] = {0,0,1,2,2,3,4,5,6,8,8,9,10,11,11,13,14};
__constant__ int c_e2[17] = {1,4,2,3,5,4,12,6,7,9,12,10,11,12,13,14,15};
__constant__ int c_p0[24] = {1,0,1,1,3,2,0,0,3,2,5,5,9,8,9,10,10,12,4,4,8,11,13,13};
__constant__ int c_p1[24] = {4,2,3,5,5,4,3,12,12,6,7,6,12,10,11,11,13,13,8,11,11,14,15,14};
__constant__ int c_ni[24] = {0,1,2,2,2,3,4,4,4,5,6,7,8,9,10,11,11,11,12,12,12,13,14,15};

// 9 ordered products s: E-scale combo c_s, j-side (right C), left-side (stage-2 C)
__constant__ int c_cOf[9]   = {0,1,1,2,2,3,4,4,5};
__constant__ int c_jside[9] = {0,1,0,2,0,1,2,1,2};
__constant__ int c_left[9]  = {0,0,1,0,2,1,1,2,2};
__constant__ int c_ca[6] = {0,0,0,1,1,2};
__constant__ int c_cb[6] = {0,1,2,1,2,2};

// monotonic float<->uint encoding for atomicMin/Max on floats
__device__ __forceinline__ unsigned encf(float f) {
  unsigned u = __float_as_uint(f);
  return (u & 0x80000000u) ? ~u : (u | 0x80000000u);
}
__device__ __forceinline__ float decf(unsigned e) {
  unsigned u = (e & 0x80000000u) ? (e & 0x7FFFFFFFu) : ~e;
  return __uint_as_float(u);
}

__global__ void k_init(unsigned* __restrict__ mm) {
  mm[0] = 0xFFFFFFFFu;  // running min (encoded)
  mm[1] = 0u;           // running max (encoded)
}

// ---- kernel 1: per-batch ovl (8x8) = sum_s pref_s * C_left^T E_c C_jside ----
__global__ __launch_bounds__(256, 4)
void k_ovl(const float* __restrict__ pos, const float* __restrict__ cg,
           const float* __restrict__ sigp, float* __restrict__ xout,
           unsigned* __restrict__ mm) {
  __shared__ float posS[48];
  __shared__ __align__(16) float P4[81][4];       // xyz + r2 in w
  __shared__ __align__(16) float CT[3][81][8];    // C' transposed per block: CT[s][j][q]
  __shared__ __align__(16) float Vall[9][81][8];  // V rows for all 9 products
  __shared__ float nInvL[9], prefL[9];
  __shared__ float red[4][64];

  const int b = blockIdx.x;
  const int t = threadIdx.x;

  if (t < 48) posS[t] = pos[b * 48 + t];

  // make_opposite_blocks forward: odd cross cols (bp>=33, odd offset) = -C[:,col-1]
  for (int idx = t; idx < 3 * 81 * 8; idx += 256) {
    int s = idx / 648;
    int rem = idx - s * 648;
    int j = rem >> 3, q = rem & 7;
    int col = s * 81 + j;
    int off = j - 33;                 // block-local position minus N1
    float v;
    if (off >= 0 && (off & 1)) v = -cg[q * 243 + (col - 1)];
    else                       v =  cg[q * 243 + col];
    CT[s][j][q] = v;
  }

  if (t == 0) {
    float sg[3];
    sg[0] = 0.4f * __expf(sigp[0]);
    sg[1] = 0.8f * __expf(sigp[1]);
    sg[2] = 1.2f * __expf(sigp[2]);
    float nI[6], pf[6];
    #pragma unroll
    for (int c = 0; c < 6; ++c) {
      float sa = sg[c_ca[c]], sb = sg[c_cb[c]];
      float s2 = sa * sa + sb * sb;
      float rr = 2.0f * sa * sb / s2;
      pf[c] = rr * sqrtf(rr);
      nI[c] = (-0.5f / s2) * 1.44269504088896f;   // fold log2(e): exp(x)=exp2(x*log2e)
    }
    #pragma unroll
    for (int s = 0; s < 9; ++s) {
      nInvL[s] = nI[c_cOf[s]];
      prefL[s] = pf[c_cOf[s]];
    }
  }
  __syncthreads();

  // 81 block points: 16 atoms, 17 bond midpoints, 24 pairs x 2 cross points
  if (t < 81) {
    float x, y, z;
    if (t < 16) {
      x = posS[t * 3]; y = posS[t * 3 + 1]; z = posS[t * 3 + 2];
    } else if (t < 33) {
      int e = t - 16;
      int a0 = c_e1[e] * 3, a1 = c_e2[e] * 3;
      x = 0.5f * (posS[a0] + posS[a1]);
      y = 0.5f * (posS[a0 + 1] + posS[a1 + 1]);
      z = 0.5f * (posS[a0 + 2] + posS[a1 + 2]);
    } else {
      int k = (t - 33) >> 1, sgn = (t - 33) & 1;
      float sc = sgn ? 0.25f : -0.25f;
      int n = c_ni[k] * 3, a0 = c_p0[k] * 3, a1 = c_p1[k] * 3;
      x = posS[n]     + sc * (posS[a0]     - posS[a1]);
      y = posS[n + 1] + sc * (posS[a0 + 1] - posS[a1 + 1]);
      z = posS[n + 2] + sc * (posS[a0 + 2] - posS[a1 + 2]);
    }
    P4[t][0] = x; P4[t][1] = y; P4[t][2] = z;
    P4[t][3] = x * x + y * y + z * z;
  }
  __syncthreads();

  // ---- V phase: 243 tasks = (product s, 3-row strip); one round, no atomics ----
  if (t < 243) {
    const int s = t / 27;
    const int i0 = (t - s * 27) * 3;
    const int js = c_jside[s];
    const float nInv = nInvL[s];          // includes log2(e)
    const float m2 = -2.0f * nInv;
    const float4 pA = *(const float4*)P4[i0];
    const float4 pB = *(const float4*)P4[i0 + 1];
    const float4 pC = *(const float4*)P4[i0 + 2];
    const float cA = pA.w * nInv, cB = pB.w * nInv, cC = pC.w * nInv;
    float aA0=0,aA1=0,aA2=0,aA3=0,aA4=0,aA5=0,aA6=0,aA7=0;
    float aB0=0,aB1=0,aB2=0,aB3=0,aB4=0,aB5=0,aB6=0,aB7=0;
    float aC0=0,aC1=0,aC2=0,aC3=0,aC4=0,aC5=0,aC6=0,aC7=0;
    #pragma unroll 3
    for (int j = 0; j < 81; ++j) {
      const float4 pj = *(const float4*)P4[j];
      const float rj = pj.w * nInv;
      const float dA = pA.x * pj.x + pA.y * pj.y + pA.z * pj.z;
      const float dB = pB.x * pj.x + pB.y * pj.y + pB.z * pj.z;
      const float dC = pC.x * pj.x + pC.y * pj.y + pC.z * pj.z;
      const float eA = EXP2(fmaf(m2, dA, cA + rj));
      const float eB = EXP2(fmaf(m2, dB, cB + rj));
      const float eC = EXP2(fmaf(m2, dC, cC + rj));
      const float4 cb0 = *(const float4*)&CT[js][j][0];
      const float4 cb1 = *(const float4*)&CT[js][j][4];
      aA0 += eA * cb0.x; aA1 += eA * cb0.y; aA2 += eA * cb0.z; aA3 += eA * cb0.w;
      aA4 += eA * cb1.x; aA5 += eA * cb1.y; aA6 += eA * cb1.z; aA7 += eA * cb1.w;
      aB0 += eB * cb0.x; aB1 += eB * cb0.y; aB2 += eB * cb0.z; aB3 += eB * cb0.w;
      aB4 += eB * cb1.x; aB5 += eB * cb1.y; aB6 += eB * cb1.z; aB7 += eB * cb1.w;
      aC0 += eC * cb0.x; aC1 += eC * cb0.y; aC2 += eC * cb0.z; aC3 += eC * cb0.w;
      aC4 += eC * cb1.x; aC5 += eC * cb1.y; aC6 += eC * cb1.z; aC7 += eC * cb1.w;
    }
    float4* vo = (float4*)&Vall[s][i0][0];
    vo[0] = make_float4(aA0, aA1, aA2, aA3);
    vo[1] = make_float4(aA4, aA5, aA6, aA7);
    vo[2] = make_float4(aB0, aB1, aB2, aB3);
    vo[3] = make_float4(aB4, aB5, aB6, aB7);
    vo[4] = make_float4(aC0, aC1, aC2, aC3);
    vo[5] = make_float4(aC4, aC5, aC6, aC7);
  }
  __syncthreads();

  // ---- stage 2: ovl[p][q] = sum_s pref_s sum_i CT[left_s][i][p]*Vall[s][i][q]
  {
    const int w = t >> 6;
    const int pos64 = t & 63;
    const int p = pos64 >> 3, q = pos64 & 7;
    float part = 0.0f;
    for (int s = w; s < 9; s += 4) {
      const int lf = c_left[s];
      const float pf = prefL[s];
      float ss = 0.0f;
      #pragma unroll 9
      for (int i = 0; i < 81; ++i)
        ss += CT[lf][i][p] * Vall[s][i][q];
      part += pf * ss;
    }
    red[w][pos64] = part;
  }
  __syncthreads();

  if (t < 64) {
    const float v = red[0][t] + red[1][t] + red[2][t] + red[3][t];
    xout[b * 64 + t] = v;
    float vmin = v, vmax = v;
    #pragma unroll
    for (int off = 32; off; off >>= 1) {
      vmin = fminf(vmin, __shfl_down(vmin, off));
      vmax = fmaxf(vmax, __shfl_down(vmax, off));
    }
    if (t == 0) {
      atomicMin(&mm[0], encf(vmin));
      atomicMax(&mm[1], encf(vmax));
    }
  }
}

// ---- kernel 2: tabulate f(x) at NT nodes; full fp32 MLP per node ----
__device__ __forceinline__ float dot128(const float* __restrict__ W,
                                        const float* __restrict__ act, int t) {
  const float4* w4 = (const float4*)(W + (size_t)t * 128);
  const float4* a4 = (const float4*)act;
  float acc = 0.0f;
  #pragma unroll
  for (int kq = 0; kq < 32; ++kq) {
    float4 w = w4[kq];
    float4 a = a4[kq];
    acc += w.x * a.x + w.y * a.y + w.z * a.z + w.w * a.w;
  }
  return acc;
}

__global__ __launch_bounds__(128)
void k_table(const float* __restrict__ ew, const float* __restrict__ eb,
             const float* __restrict__ mup, const float* __restrict__ lrp,
             const float* __restrict__ W1, const float* __restrict__ b1,
             const float* __restrict__ W2, const float* __restrict__ b2,
             const float* __restrict__ W3, const float* __restrict__ b3,
             const unsigned* __restrict__ mm, float* __restrict__ table) {
  __shared__ __align__(16) float actA[128];
  __shared__ __align__(16) float actB[128];
  __shared__ float red[2];
  __shared__ float red2[2];
  const int t = threadIdx.x;
  const int wv = t >> 6;

  const float xmin = decf(mm[0]);
  const float xmax = decf(mm[1]);
  const float x = xmin + (xmax - xmin) * ((float)blockIdx.x / (float)(NT - 1));

  // encoder softmax: e = softmax(ew*x + eb)
  float lg = ew[t] * x + eb[t];
  float m = lg;
  #pragma unroll
  for (int off = 32; off; off >>= 1) m = fmaxf(m, __shfl_xor(m, off));
  if ((t & 63) == 0) red[wv] = m;
  __syncthreads();
  m = fmaxf(red[0], red[1]);
  float ev = __expf(lg - m);
  float s = ev;
  #pragma unroll
  for (int off = 32; off; off >>= 1) s += __shfl_xor(s, off);
  if ((t & 63) == 0) red2[wv] = s;
  __syncthreads();
  s = red2[0] + red2[1];
  actA[t] = ev / s;
  __syncthreads();

  // layer 1 (relu)
  float h = fmaxf(b1[t] + dot128(W1, actA, t), 0.0f);
  actB[t] = h;
  __syncthreads();
  // layer 2 (relu)
  h = fmaxf(b2[t] + dot128(W2, actB, t), 0.0f);
  actA[t] = h;
  __syncthreads();
  // layer 3 (linear)
  float h3 = b3[t] + dot128(W3, actA, t);

  // p = softmax(h3); mu = p . mu_proj  (fused)
  float m3 = h3;
  #pragma unroll
  for (int off = 32; off; off >>= 1) m3 = fmaxf(m3, __shfl_xor(m3, off));
  __syncthreads();
  if ((t & 63) == 0) red[wv] = m3;
  __syncthreads();
  m3 = fmaxf(red[0], red[1]);
  float e3 = __expf(h3 - m3);
  float dn = e3;
  float nm = e3 * mup[t];
  #pragma unroll
  for (int off = 32; off; off >>= 1) {
    dn += __shfl_xor(dn, off);
    nm += __shfl_xor(nm, off);
  }
  __syncthreads();
  if ((t & 63) == 0) { red[wv] = dn; red2[wv] = nm; }
  __syncthreads();
  if (t == 0)
    table[blockIdx.x] = lrp[0] * ((red2[0] + red2[1]) / (red[0] + red[1]));
}

// ---- kernel 3: linear interpolation of the table at each x ----
__global__ __launch_bounds__(256)
void k_interp(const float* __restrict__ xbuf, const float* __restrict__ table,
              const unsigned* __restrict__ mm, float* __restrict__ out, int n) {
  const int r = blockIdx.x * 256 + threadIdx.x;
  if (r >= n) return;
  const float xmin = decf(mm[0]);
  const float xmax = decf(mm[1]);
  const float range = xmax - xmin;
  const float scale = (range > 0.0f) ? (float)(NT - 1) / range : 0.0f;
  float p = (xbuf[r] - xmin) * scale;
  int i0 = (int)floorf(p);
  i0 = min(max(i0, 0), NT - 2);
  const float w = p - (float)i0;
  out[r] = table[i0] + w * (table[i0 + 1] - table[i0]);
}

extern "C" void kernel_launch(void* const* d_in, const int* in_sizes, int n_in,
                              void* d_out, int out_size, void* d_ws, size_t ws_size,
                              hipStream_t stream) {
  const float* pos  = (const float*)d_in[0];
  const float* cg   = (const float*)d_in[1];
  const float* sigp = (const float*)d_in[2];
  const float* ew   = (const float*)d_in[3];
  const float* eb   = (const float*)d_in[4];
  const float* mup  = (const float*)d_in[5];
  const float* lrp  = (const float*)d_in[6];
  const float* W1   = (const float*)d_in[7];
  const float* b1   = (const float*)d_in[8];
  const float* W2   = (const float*)d_in[9];
  const float* b2   = (const float*)d_in[10];
  const float* W3   = (const float*)d_in[11];
  const float* b3   = (const float*)d_in[12];
  float* out = (float*)d_out;

  // workspace: [0..1] uint min/max (encoded), xbuf[65536] @ +16 floats, table[NT]
  unsigned* mm = (unsigned*)d_ws;
  float* xbuf  = (float*)d_ws + 16;
  float* table = xbuf + NOUT;

  k_init<<<1, 1, 0, stream>>>(mm);
  k_ovl<<<NBATCH, 256, 0, stream>>>(pos, cg, sigp, xbuf, mm);
  k_table<<<NT, 128, 0, stream>>>(ew, eb, mup, lrp, W1, b1, W2, b2, W3, b3, mm, table);
  k_interp<<<(NOUT + 255) / 256, 256, 0, stream>>>(xbuf, table, mm, out, NOUT);
}